// Round 1
// baseline (1190.172 us; speedup 1.0000x reference)
//
#include <hip/hip_runtime.h>

// 16-qubit, depth-4, batch-512 statevector simulator.
// State: 512 x 65536 complex64 = 256 MiB in d_ws.
// Reference qubit q <-> flat-index bit beta = 15-q.
// Memory layout per batch: amp with basis index g stored at m = (g>>3) | ((g&7)<<13)
// so that both pass windows see contiguous chunks.
// Pass A (window bits 3..15): 1q gates qubits 0..12 + CNOT chain prefix (12 CNOTs),
//   chain perm folded into write: final[j] = S[j ^ ((j>>1)&0xFFF)].
// Pass B (window bits {0..11,15}): 1q gates qubits 13..15 + CNOTs (q12,q13),(q13,q14),
//   (q14,q15),(q15,q0); perm: i = j ^ ((j>>1)&0x0E00) ^ ((j&1)<<12).
// Layer-0 pass A generates the product state (16 RX gates) analytically.
// Layer-3 pass B computes expZ and atomically accumulates into d_out.

#define NQ 16
#define CH_BITS 13
#define CH (1 << CH_BITS)   // 8192 amps per block chunk (64 KB LDS)
#define TPB 256

typedef float2 cplx;

__device__ __forceinline__ cplx cmadd2(cplx u, cplx a, cplx v, cplx b) {
    // u*a + v*b (complex)
    return make_float2(u.x*a.x - u.y*a.y + v.x*b.x - v.y*b.y,
                       u.x*a.y + u.y*a.x + v.x*b.y + v.y*b.x);
}

// U = RY(t2) * RX(t1) * RZ(t0), row-major [u00,u01,u10,u11]
__device__ __forceinline__ void computeU(const float* params, int layer, int q, cplx* U) {
    const float* p = params + (layer*NQ + q)*3;
    float s0, c0, s1, c1, s2, c2;
    sincosf(0.5f*p[0], &s0, &c0);
    sincosf(0.5f*p[1], &s1, &c1);
    sincosf(0.5f*p[2], &s2, &c2);
    // RZ = diag(c0 - i s0, c0 + i s0); M = RX * RZ
    cplx m00 = make_float2( c1*c0, -c1*s0);
    cplx m01 = make_float2( s1*s0, -s1*c0);   // (-i s1)*(c0 + i s0)
    cplx m10 = make_float2(-s1*s0, -s1*c0);   // (-i s1)*(c0 - i s0)
    cplx m11 = make_float2( c1*c0,  c1*s0);
    U[0] = make_float2(c2*m00.x - s2*m10.x, c2*m00.y - s2*m10.y);
    U[1] = make_float2(c2*m01.x - s2*m11.x, c2*m01.y - s2*m11.y);
    U[2] = make_float2(s2*m00.x + c2*m10.x, s2*m00.y + c2*m10.y);
    U[3] = make_float2(s2*m01.x + c2*m11.x, s2*m01.y + c2*m11.y);
}

__global__ __launch_bounds__(TPB) void qc_passA(
    const float* __restrict__ x, const float* __restrict__ params,
    float2* __restrict__ st, int layer, int first)
{
    __shared__ float2 S[CH];
    __shared__ cplx Ush[13][4];
    __shared__ float cb[NQ], sb[NQ];
    __shared__ float tlo[256], thi[256];

    const int t    = threadIdx.x;
    const int b    = blockIdx.x >> 3;
    const int fix3 = blockIdx.x & 7;        // g bits 0..2
    float2* base = st + ((size_t)b << NQ) + (fix3 << CH_BITS);

    // local bit lb <-> g bit lb+3 <-> qubit 12-lb
    if (t < 13) computeU(params, layer, 12 - t, Ush[t]);

    if (first) {
        if (t < NQ) {                        // bit beta = t, qubit 15-t
            float h = 0.5f * x[b*NQ + (15 - t)];
            sb[t] = sinf(h); cb[t] = cosf(h);
        }
        __syncthreads();
        float plo = 1.f, phi = 1.f;
        #pragma unroll
        for (int q = 0; q < 8; ++q) {
            plo *= ((t >> q) & 1) ? sb[q]   : cb[q];
            phi *= ((t >> q) & 1) ? sb[8+q] : cb[8+q];
        }
        tlo[t] = plo; thi[t] = phi;
        __syncthreads();
        for (int k = 0; k < CH/TPB; ++k) {
            int j = t + k*TPB;
            int g = (j << 3) | fix3;
            float r = tlo[g & 255] * thi[g >> 8];
            int pc = __popc(g) & 3;          // phase (-i)^pc
            float re = (pc == 0) ? r : ((pc == 2) ? -r : 0.f);
            float im = (pc == 1) ? -r : ((pc == 3) ? r : 0.f);
            S[j] = make_float2(re, im);
        }
    } else {
        const float4* src = (const float4*)base;
        for (int k = 0; k < CH/2/TPB; ++k) {
            int j4 = t + k*TPB;
            float4 v = src[j4];
            S[2*j4]   = make_float2(v.x, v.y);
            S[2*j4+1] = make_float2(v.z, v.w);
        }
    }
    __syncthreads();

    // gate-pair on local bits (0,1): 4 contiguous amps -> float4 LDS (conflict-free)
    {
        cplx ua00=Ush[0][0], ua01=Ush[0][1], ua10=Ush[0][2], ua11=Ush[0][3];
        cplx ub00=Ush[1][0], ub01=Ush[1][1], ub10=Ush[1][2], ub11=Ush[1][3];
        float4* S4 = (float4*)S;
        for (int k = 0; k < CH/4/TPB; ++k) {
            int m = t + k*TPB;
            float4 v0 = S4[2*m], v1 = S4[2*m+1];
            cplx A00 = make_float2(v0.x, v0.y), A01 = make_float2(v0.z, v0.w);
            cplx A10 = make_float2(v1.x, v1.y), A11 = make_float2(v1.z, v1.w);
            cplx n00 = cmadd2(ua00, A00, ua01, A01);
            cplx n01 = cmadd2(ua10, A00, ua11, A01);
            cplx n10 = cmadd2(ua00, A10, ua01, A11);
            cplx n11 = cmadd2(ua10, A10, ua11, A11);
            A00 = cmadd2(ub00, n00, ub01, n10);
            A10 = cmadd2(ub10, n00, ub11, n10);
            A01 = cmadd2(ub00, n01, ub01, n11);
            A11 = cmadd2(ub10, n01, ub11, n11);
            S4[2*m]   = make_float4(A00.x, A00.y, A01.x, A01.y);
            S4[2*m+1] = make_float4(A10.x, A10.y, A11.x, A11.y);
        }
    }
    __syncthreads();

    // gate-pairs on local bits (2,3),(4,5),(6,7),(8,9),(10,11)
    for (int gp = 1; gp < 6; ++gp) {
        int qa = 2*gp;
        cplx ua00=Ush[qa][0],   ua01=Ush[qa][1],   ua10=Ush[qa][2],   ua11=Ush[qa][3];
        cplx ub00=Ush[qa+1][0], ub01=Ush[qa+1][1], ub10=Ush[qa+1][2], ub11=Ush[qa+1][3];
        int maskLo = (1 << qa) - 1;
        for (int k = 0; k < CH/4/TPB; ++k) {
            int m = t + k*TPB;
            int i00 = ((m >> qa) << (qa+2)) | (m & maskLo);
            int i01 = i00 | (1 << qa);
            int i10 = i00 | (2 << qa);
            int i11 = i00 | (3 << qa);
            cplx A00 = S[i00], A01 = S[i01], A10 = S[i10], A11 = S[i11];
            cplx n00 = cmadd2(ua00, A00, ua01, A01);
            cplx n01 = cmadd2(ua10, A00, ua11, A01);
            cplx n10 = cmadd2(ua00, A10, ua01, A11);
            cplx n11 = cmadd2(ua10, A10, ua11, A11);
            S[i00] = cmadd2(ub00, n00, ub01, n10);
            S[i10] = cmadd2(ub10, n00, ub11, n10);
            S[i01] = cmadd2(ub00, n01, ub01, n11);
            S[i11] = cmadd2(ub10, n01, ub11, n11);
        }
        __syncthreads();
    }

    // single gate on local bit 12
    {
        cplx u00=Ush[12][0], u01=Ush[12][1], u10=Ush[12][2], u11=Ush[12][3];
        for (int k = 0; k < CH/2/TPB; ++k) {
            int p = t + k*TPB;               // 0..4095
            cplx A = S[p], B = S[p | 4096];
            S[p]        = cmadd2(u00, A, u01, B);
            S[p | 4096] = cmadd2(u10, A, u11, B);
        }
    }
    __syncthreads();

    // write back, folding 12-CNOT chain perm: final[j] = S[j ^ ((j>>1)&0xFFF)]
    float4* dst = (float4*)base;
    for (int k = 0; k < CH/2/TPB; ++k) {
        int j4 = t + k*TPB;
        int j0 = 2*j4;
        int i0 = j0 ^ ((j0 >> 1) & 0x0FFF);
        int j1 = j0 + 1;
        int i1 = j1 ^ ((j1 >> 1) & 0x0FFF);
        cplx a = S[i0], c = S[i1];
        dst[j4] = make_float4(a.x, a.y, c.x, c.y);
    }
}

__global__ __launch_bounds__(TPB) void qc_passB(
    const float* __restrict__ params, float2* __restrict__ st,
    float* __restrict__ out, int layer, int last)
{
    __shared__ float2 S[CH];
    __shared__ cplx Ush[3][4];

    const int t    = threadIdx.x;
    const int b    = blockIdx.x >> 3;
    const int fixb = blockIdx.x & 7;         // g bits 12..14
    float2* base = st + ((size_t)b << NQ);

    // local j: bits 0..8 = g bits 3..11, bit 9 = g bit 15, bits 10..12 = g bits 0..2
    // local bit 10 <-> qubit 15 (Ush[0]), 11 <-> q14 (Ush[1]), 12 <-> q13 (Ush[2])
    if (t < 3) computeU(params, layer, 15 - t, Ush[t]);

    for (int k = 0; k < CH/2/TPB; ++k) {
        int jp = t + k*TPB;
        int j = 2*jp;
        int m = (j & 511) | (fixb << 9) | (((j >> 9) & 1) << 12) | ((j >> 10) << 13);
        float4 v = *(const float4*)(base + m);
        S[j]   = make_float2(v.x, v.y);
        S[j+1] = make_float2(v.z, v.w);
    }
    __syncthreads();

    // gate-pair on local bits (10,11)
    {
        cplx ua00=Ush[0][0], ua01=Ush[0][1], ua10=Ush[0][2], ua11=Ush[0][3];
        cplx ub00=Ush[1][0], ub01=Ush[1][1], ub10=Ush[1][2], ub11=Ush[1][3];
        for (int k = 0; k < CH/4/TPB; ++k) {
            int m = t + k*TPB;
            int i00 = ((m >> 10) << 12) | (m & 1023);
            int i01 = i00 | (1 << 10);
            int i10 = i00 | (2 << 10);
            int i11 = i00 | (3 << 10);
            cplx A00 = S[i00], A01 = S[i01], A10 = S[i10], A11 = S[i11];
            cplx n00 = cmadd2(ua00, A00, ua01, A01);
            cplx n01 = cmadd2(ua10, A00, ua11, A01);
            cplx n10 = cmadd2(ua00, A10, ua01, A11);
            cplx n11 = cmadd2(ua10, A10, ua11, A11);
            S[i00] = cmadd2(ub00, n00, ub01, n10);
            S[i10] = cmadd2(ub10, n00, ub11, n10);
            S[i01] = cmadd2(ub00, n01, ub01, n11);
            S[i11] = cmadd2(ub10, n01, ub11, n11);
        }
    }
    __syncthreads();

    // single gate on local bit 12 (qubit 13)
    {
        cplx u00=Ush[2][0], u01=Ush[2][1], u10=Ush[2][2], u11=Ush[2][3];
        for (int k = 0; k < CH/2/TPB; ++k) {
            int p = t + k*TPB;
            cplx A = S[p], B = S[p | 4096];
            S[p]        = cmadd2(u00, A, u01, B);
            S[p | 4096] = cmadd2(u10, A, u11, B);
        }
    }
    __syncthreads();

    // perm for CNOTs (q12,q13),(q13,q14),(q14,q15),(q15,q0):
    // i = j ^ ((j>>1)&0x0E00) ^ ((j&1)<<12)
    if (!last) {
        for (int k = 0; k < CH/2/TPB; ++k) {
            int jp = t + k*TPB;
            int j0 = 2*jp;
            int i0 = j0 ^ ((j0 >> 1) & 0x0E00);
            int j1 = j0 + 1;
            int i1 = j1 ^ ((j1 >> 1) & 0x0E00) ^ (1 << 12);
            int m = (j0 & 511) | (fixb << 9) | (((j0 >> 9) & 1) << 12) | ((j0 >> 10) << 13);
            cplx a = S[i0], c = S[i1];
            *(float4*)(base + m) = make_float4(a.x, a.y, c.x, c.y);
        }
    } else {
        // expZ epilogue. Thread's amps: j = 2t+o+512k -> g bits 3..11 fixed (=2t+o),
        // g bits 0..2 = k>>1, g bit 15 = k&1, g bits 12..14 = fixb.
        float accT = 0.f, a15 = 0.f, a0 = 0.f, a1 = 0.f, a2 = 0.f, a3 = 0.f;
        for (int k = 0; k < CH/2/TPB; ++k) {
            int jp = t + k*TPB;
            #pragma unroll
            for (int o = 0; o < 2; ++o) {
                int j = 2*jp + o;
                int i = j ^ ((j >> 1) & 0x0E00) ^ ((j & 1) << 12);
                cplx a = S[i];
                float p = a.x*a.x + a.y*a.y;
                accT += p;
                a15 += ((k & 1) ? -p : p);        // g bit 15
                a0  += (((k >> 1) & 1) ? -p : p); // g bit 0
                a1  += (((k >> 2) & 1) ? -p : p); // g bit 1
                a2  += (((k >> 3) & 1) ? -p : p); // g bit 2
                a3  += (o ? -p : p);              // g bit 3
            }
        }
        // out[b,q] uses sign of g bit (15-q)
        float acc[NQ];
        #pragma unroll
        for (int q = 0; q < NQ; ++q) {
            int beta = 15 - q;
            float v;
            if      (beta == 15) v = a15;
            else if (beta == 0)  v = a0;
            else if (beta == 1)  v = a1;
            else if (beta == 2)  v = a2;
            else if (beta == 3)  v = a3;
            else if (beta <= 11) v = ((t >> (beta - 4)) & 1) ? -accT : accT;
            else                 v = ((fixb >> (beta - 12)) & 1) ? -accT : accT;
            acc[q] = v;
        }
        #pragma unroll
        for (int q = 0; q < NQ; ++q) {
            float v = acc[q];
            v += __shfl_down(v, 32, 64);
            v += __shfl_down(v, 16, 64);
            v += __shfl_down(v,  8, 64);
            v += __shfl_down(v,  4, 64);
            v += __shfl_down(v,  2, 64);
            v += __shfl_down(v,  1, 64);
            acc[q] = v;
        }
        if ((t & 63) == 0) {
            #pragma unroll
            for (int q = 0; q < NQ; ++q)
                atomicAdd(&out[b*NQ + q], acc[q]);
        }
    }
}

extern "C" void kernel_launch(void* const* d_in, const int* in_sizes, int n_in,
                              void* d_out, int out_size, void* d_ws, size_t ws_size,
                              hipStream_t stream)
{
    (void)in_sizes; (void)n_in; (void)ws_size;
    const float* x      = (const float*)d_in[0];   // (512,16) fp32
    const float* params = (const float*)d_in[1];   // (4,16,3) fp32
    float* out = (float*)d_out;                    // (512,16) fp32
    float2* st = (float2*)d_ws;                    // 256 MiB state

    hipMemsetAsync(d_out, 0, (size_t)out_size * sizeof(float), stream);
    for (int l = 0; l < 4; ++l) {
        qc_passA<<<dim3(512*8), dim3(TPB), 0, stream>>>(x, params, st, l, (l == 0) ? 1 : 0);
        qc_passB<<<dim3(512*8), dim3(TPB), 0, stream>>>(params, st, out, l, (l == 3) ? 1 : 0);
    }
}

// Round 2
// 803.105 us; speedup vs baseline: 1.4820x; 1.4820x over previous
//
#include <hip/hip_runtime.h>

// 16-qubit, depth-4, batch-512 statevector simulator — register-resident version.
// State: 512 x 65536 complex64 = 256 MiB in d_ws (L3-resident).
// Reference qubit q <-> flat-index bit beta = 15-q.
// Memory layout per batch: amp with basis index g stored at m = (g>>3) | ((g&7)<<13).
//
// passA (window = g bits 3..15 as local j bits 0..12; fix3 = g bits 0..2):
//   Each thread holds 32 amps in registers. Ownership arrangements:
//     arr1 {0,9,10,11,12} (qubits 12,3,2,1,0) -> transpose -> arr2 {1,2,3,4,12}
//     (qubits 11,10,9,8) -> transpose -> arr3 {5,6,7,8,12} (qubits 7,6,5,4)
//   Writeback folds the 12-CNOT chain perm final[j] = S[j ^ ((j>>1)&0xFFF)].
//   Transposes staged through a 32 KB LDS buffer in 2 rounds split by bit 12
//   (bit 12 is thread-owned in every arrangement and preserved by the perm).
//   LDS slot swizzle: slot(j) = j ^ (((j>>5)&7)<<1) — dense-equivalent banks
//   for every access pattern used here.
// passB (3 gates on local bits 10,11,12 = qubits 15,14,13 + CNOT tail perm):
//   perm i = d ^ ((d>>1)&0x0E00) ^ ((d&1)<<12) only mixes thread-owned bits
//   {0,9..12}; i bits 1..8 = d bits 1..8  => pure register kernel, zero LDS.
// Layer-0 passA generates the RX product state analytically in registers.
// Layer-3 passB computes expZ (signs read off dest-index bits) + atomicAdd.

#define NQ 16
#define TPB 256

typedef float2 cplx;

__device__ __forceinline__ cplx cmadd2(cplx u, cplx a, cplx v, cplx b) {
    return make_float2(u.x*a.x - u.y*a.y + v.x*b.x - v.y*b.y,
                       u.x*a.y + u.y*a.x + v.x*b.y + v.y*b.x);
}

// U = RY(t2) * RX(t1) * RZ(t0), row-major [u00,u01,u10,u11]
__device__ __forceinline__ void computeU(const float* params, int layer, int q, cplx* U) {
    const float* p = params + (layer*NQ + q)*3;
    float s0, c0, s1, c1, s2, c2;
    sincosf(0.5f*p[0], &s0, &c0);
    sincosf(0.5f*p[1], &s1, &c1);
    sincosf(0.5f*p[2], &s2, &c2);
    cplx m00 = make_float2( c1*c0, -c1*s0);
    cplx m01 = make_float2( s1*s0, -s1*c0);
    cplx m10 = make_float2(-s1*s0, -s1*c0);
    cplx m11 = make_float2( c1*c0,  c1*s0);
    U[0] = make_float2(c2*m00.x - s2*m10.x, c2*m00.y - s2*m10.y);
    U[1] = make_float2(c2*m01.x - s2*m11.x, c2*m01.y - s2*m11.y);
    U[2] = make_float2(s2*m00.x + c2*m10.x, s2*m00.y + c2*m10.y);
    U[3] = make_float2(s2*m01.x + c2*m11.x, s2*m01.y + c2*m11.y);
}

// 1q gate on register array A[32], pairing a <-> a|MASK (MASK = in-thread bit).
template<int MASK>
__device__ __forceinline__ void gate32(cplx* A, cplx u00, cplx u01, cplx u10, cplx u11) {
    #pragma unroll
    for (int a = 0; a < 32; ++a) {
        if (!(a & MASK)) {
            cplx xx = A[a], yy = A[a | MASK];
            A[a]        = cmadd2(u00, xx, u01, yy);
            A[a | MASK] = cmadd2(u10, xx, u11, yy);
        }
    }
}

// passB register perm: dest reg ad -> source reg (bits: i0=d0, i9=d9^d10,
// i10=d10^d11, i11=d11^d12, i12=d12^d0; reg bits = (d0, d9..d12)).
__device__ __forceinline__ constexpr int permB(int ad) {
    return (ad & 1)
         | ((((ad >> 1) ^ (ad >> 2)) & 1) << 1)
         | ((((ad >> 2) ^ (ad >> 3)) & 1) << 2)
         | ((((ad >> 3) ^ (ad >> 4)) & 1) << 3)
         | ((((ad >> 4) ^  ad      ) & 1) << 4);
}

__global__ __launch_bounds__(TPB) void qc_passA(
    const float* __restrict__ x, const float* __restrict__ params,
    float2* __restrict__ st, int layer, int first)
{
    __shared__ __align__(16) float2 S[4096];   // 32 KB, one bit-12 half at a time
    __shared__ cplx Ush[13][4];
    __shared__ float cb[NQ], sb[NQ];

    const int t    = threadIdx.x;
    const int b    = blockIdx.x >> 3;
    const int fix3 = blockIdx.x & 7;            // g bits 0..2
    float2* base = st + ((size_t)b << NQ) + (fix3 << 13);

    if (t < 13) computeU(params, layer, 12 - t, Ush[t]);

    // arr1: register a = o | (k<<1); j = o | (t<<1) | (k<<9); owned j bits {0,9,10,11,12}
    cplx A[32];
    if (first) {
        if (t < NQ) {                            // g bit beta = t, qubit 15-t
            float hh = 0.5f * x[b*NQ + (15 - t)];
            sb[t] = sinf(hh); cb[t] = cosf(hh);
        }
        __syncthreads();
        // fixed factors: g bits 0..2 = fix3, g bits 4..11 = t
        float pf = 1.f;
        #pragma unroll
        for (int bet = 0; bet < 3; ++bet) pf *= ((fix3 >> bet) & 1) ? sb[bet] : cb[bet];
        #pragma unroll
        for (int bet = 4; bet < 12; ++bet) pf *= ((t >> (bet - 4)) & 1) ? sb[bet] : cb[bet];
        int pcT = __popc(fix3) + __popc(t & 255);
        #pragma unroll
        for (int a = 0; a < 32; ++a) {
            // g bit 3 = a&1, g bits 12..15 = a>>1
            float r = pf * ((a & 1) ? sb[3] : cb[3]);
            r *= (((a >> 1) & 1) ? sb[12] : cb[12]);
            r *= (((a >> 2) & 1) ? sb[13] : cb[13]);
            r *= (((a >> 3) & 1) ? sb[14] : cb[14]);
            r *= (((a >> 4) & 1) ? sb[15] : cb[15]);
            int pc = (pcT + __popc(a)) & 3;      // phase (-i)^pc
            float re = (pc == 0) ? r : ((pc == 2) ? -r : 0.f);
            float im = (pc == 1) ? -r : ((pc == 3) ? r : 0.f);
            A[a] = make_float2(re, im);
        }
    } else {
        const float4* src = (const float4*)base;
        #pragma unroll
        for (int k = 0; k < 16; ++k) {
            float4 v = src[t + 256*k];           // amps j = 2(t+256k)+{0,1}
            A[2*k]   = make_float2(v.x, v.y);
            A[2*k+1] = make_float2(v.z, v.w);
        }
    }
    __syncthreads();                             // Ush (and cb/sb) ready

    // arr1 gates: j0 -> qubit 12 (Ush[0]); j9,j10,j11,j12 -> qubits 3,2,1,0
    gate32<1> (A, Ush[0][0],  Ush[0][1],  Ush[0][2],  Ush[0][3]);
    gate32<2> (A, Ush[9][0],  Ush[9][1],  Ush[9][2],  Ush[9][3]);
    gate32<4> (A, Ush[10][0], Ush[10][1], Ush[10][2], Ush[10][3]);
    gate32<8> (A, Ush[11][0], Ush[11][1], Ush[11][2], Ush[11][3]);
    gate32<16>(A, Ush[12][0], Ush[12][1], Ush[12][2], Ush[12][3]);

    // Transpose 1: arr1 -> arr2 {1,2,3,4,12}; rounds by bit 12 (= reg bit 4)
    #pragma unroll
    for (int h = 0; h < 2; ++h) {
        __syncthreads();
        #pragma unroll
        for (int c = 0; c < 8; ++c) {            // write pairs: j' = (t<<1)|(c<<9)
            int slot = ((t << 1) | (c << 9)) ^ (((t >> 4) & 7) << 1);
            cplx a0 = A[h*16 + 2*c], a1 = A[h*16 + 2*c + 1];
            *(float4*)&S[slot] = make_float4(a0.x, a0.y, a1.x, a1.y);
        }
        __syncthreads();
        #pragma unroll
        for (int rr = 0; rr < 16; ++rr) {        // read arr2: j bits1..4 = rr
            int jj = (t & 1) | (rr << 1) | (((t >> 1) & 15) << 5) | (((t >> 5) & 7) << 9);
            A[h*16 + rr] = S[jj ^ (((t >> 1) & 7) << 1)];
        }
    }

    // arr2 gates: j1..j4 -> qubits 11,10,9,8 (Ush[1..4])
    gate32<1>(A, Ush[1][0], Ush[1][1], Ush[1][2], Ush[1][3]);
    gate32<2>(A, Ush[2][0], Ush[2][1], Ush[2][2], Ush[2][3]);
    gate32<4>(A, Ush[3][0], Ush[3][1], Ush[3][2], Ush[3][3]);
    gate32<8>(A, Ush[4][0], Ush[4][1], Ush[4][2], Ush[4][3]);

    // Transpose 2: arr2 -> arr3 {5,6,7,8,12}
    #pragma unroll
    for (int h = 0; h < 2; ++h) {
        __syncthreads();
        #pragma unroll
        for (int rr = 0; rr < 16; ++rr) {        // write at arr2 positions
            int jj = (t & 1) | (rr << 1) | (((t >> 1) & 15) << 5) | (((t >> 5) & 7) << 9);
            S[jj ^ (((t >> 1) & 7) << 1)] = A[h*16 + rr];
        }
        __syncthreads();
        #pragma unroll
        for (int rr = 0; rr < 16; ++rr) {        // read arr3: j bits5..8 = rr
            int jj = (t & 31) | (rr << 5) | (((t >> 5) & 7) << 9);
            A[h*16 + rr] = S[jj ^ ((rr & 7) << 1)];
        }
    }

    // arr3 gates: j5..j8 -> qubits 7,6,5,4 (Ush[5..8])
    gate32<1>(A, Ush[5][0], Ush[5][1], Ush[5][2], Ush[5][3]);
    gate32<2>(A, Ush[6][0], Ush[6][1], Ush[6][2], Ush[6][3]);
    gate32<4>(A, Ush[7][0], Ush[7][1], Ush[7][2], Ush[7][3]);
    gate32<8>(A, Ush[8][0], Ush[8][1], Ush[8][2], Ush[8][3]);

    // Writeback: stage at natural slots, read with CNOT-chain perm, store coalesced
    float4* dst = (float4*)base;
    #pragma unroll
    for (int h = 0; h < 2; ++h) {
        __syncthreads();
        #pragma unroll
        for (int rr = 0; rr < 16; ++rr) {        // write at natural (arr3) positions
            int jj = (t & 31) | (rr << 5) | (((t >> 5) & 7) << 9);
            S[jj ^ ((rr & 7) << 1)] = A[h*16 + rr];
        }
        __syncthreads();
        #pragma unroll
        for (int k = 0; k < 8; ++k) {            // dest d' = 2(t+256k), bit12 = h
            int d  = 2*(t + 256*k);
            int i0 = d ^ (d >> 1) ^ (h << 11);           // source (12-bit)
            int i1 = (d+1) ^ ((d+1) >> 1) ^ (h << 11);
            cplx a0 = S[i0 ^ (((i0 >> 5) & 7) << 1)];
            cplx a1 = S[i1 ^ (((i1 >> 5) & 7) << 1)];
            dst[(t + 256*k) | (h << 11)] = make_float4(a0.x, a0.y, a1.x, a1.y);
        }
    }
}

__global__ __launch_bounds__(TPB) void qc_passB(
    const float* __restrict__ params, float2* __restrict__ st,
    float* __restrict__ out, int layer, int last)
{
    __shared__ cplx Ush[3][4];

    const int t    = threadIdx.x;
    const int b    = blockIdx.x >> 3;
    const int fixb = blockIdx.x & 7;             // g bits 12..14
    float2* base = st + ((size_t)b << NQ);

    // local d: bits 0..8 = g bits 3..11, bit 9 = g bit 15, bits 10..12 = g bits 0..2
    if (t < 3) computeU(params, layer, 15 - t, Ush[t]);

    // registers: a = d0 | (k<<1) where k = d bits 9..12; thread owns {0,9,10,11,12}
    cplx A[32];
    #pragma unroll
    for (int k = 0; k < 16; ++k) {
        int j = 2*(t + 256*k);
        int m = (j & 511) | (fixb << 9) | (((j >> 9) & 1) << 12) | ((j >> 10) << 13);
        float4 v = *(const float4*)(base + m);
        A[2*k]   = make_float2(v.x, v.y);
        A[2*k+1] = make_float2(v.z, v.w);
    }
    __syncthreads();                             // Ush ready

    // gates: d10 (q15, Ush[0]) = reg bit 2; d11 (q14) = bit 3; d12 (q13) = bit 4
    gate32<4> (A, Ush[0][0], Ush[0][1], Ush[0][2], Ush[0][3]);
    gate32<8> (A, Ush[1][0], Ush[1][1], Ush[1][2], Ush[1][3]);
    gate32<16>(A, Ush[2][0], Ush[2][1], Ush[2][2], Ush[2][3]);

    if (!last) {
        // store with CNOT-tail perm folded (register-internal)
        #pragma unroll
        for (int k = 0; k < 16; ++k) {
            int j = 2*(t + 256*k);
            int m = (j & 511) | (fixb << 9) | (((j >> 9) & 1) << 12) | ((j >> 10) << 13);
            cplx a0 = A[permB(2*k)];
            cplx a1 = A[permB(2*k + 1)];
            *(float4*)(base + m) = make_float4(a0.x, a0.y, a1.x, a1.y);
        }
    } else {
        // expZ epilogue: dest d bits -> g bits; signs from dest reg index ad:
        // ad0 = g3, ad1 = g15, ad2 = g0, ad3 = g1, ad4 = g2
        float accT = 0.f, sg3 = 0.f, sg15 = 0.f, sg0 = 0.f, sg1 = 0.f, sg2 = 0.f;
        #pragma unroll
        for (int ad = 0; ad < 32; ++ad) {
            cplx v = A[permB(ad)];
            float p = v.x*v.x + v.y*v.y;
            accT += p;
            sg3  += (ad & 1)  ? -p : p;
            sg15 += (ad & 2)  ? -p : p;
            sg0  += (ad & 4)  ? -p : p;
            sg1  += (ad & 8)  ? -p : p;
            sg2  += (ad & 16) ? -p : p;
        }
        float acc[NQ];
        #pragma unroll
        for (int q = 0; q < NQ; ++q) {
            int beta = 15 - q;
            float v;
            if      (beta == 15) v = sg15;
            else if (beta == 0)  v = sg0;
            else if (beta == 1)  v = sg1;
            else if (beta == 2)  v = sg2;
            else if (beta == 3)  v = sg3;
            else if (beta <= 11) v = ((t >> (beta - 4)) & 1) ? -accT : accT;   // g4..11 = t
            else                 v = ((fixb >> (beta - 12)) & 1) ? -accT : accT;
            acc[q] = v;
        }
        #pragma unroll
        for (int q = 0; q < NQ; ++q) {
            float v = acc[q];
            v += __shfl_down(v, 32, 64);
            v += __shfl_down(v, 16, 64);
            v += __shfl_down(v,  8, 64);
            v += __shfl_down(v,  4, 64);
            v += __shfl_down(v,  2, 64);
            v += __shfl_down(v,  1, 64);
            acc[q] = v;
        }
        if ((t & 63) == 0) {
            #pragma unroll
            for (int q = 0; q < NQ; ++q)
                atomicAdd(&out[b*NQ + q], acc[q]);
        }
    }
}

extern "C" void kernel_launch(void* const* d_in, const int* in_sizes, int n_in,
                              void* d_out, int out_size, void* d_ws, size_t ws_size,
                              hipStream_t stream)
{
    (void)in_sizes; (void)n_in; (void)ws_size;
    const float* x      = (const float*)d_in[0];   // (512,16) fp32
    const float* params = (const float*)d_in[1];   // (4,16,3) fp32
    float* out = (float*)d_out;                    // (512,16) fp32
    float2* st = (float2*)d_ws;                    // 256 MiB state

    hipMemsetAsync(d_out, 0, (size_t)out_size * sizeof(float), stream);
    for (int l = 0; l < 4; ++l) {
        qc_passA<<<dim3(512*8), dim3(TPB), 0, stream>>>(x, params, st, l, (l == 0) ? 1 : 0);
        qc_passB<<<dim3(512*8), dim3(TPB), 0, stream>>>(params, st, out, l, (l == 3) ? 1 : 0);
    }
}